// Round 1
// baseline (239.836 us; speedup 1.0000x reference)
//
#include <hip/hip_runtime.h>
#include <hip/hip_bf16.h>
#include <math.h>

// Problem: out[b,s,d] = x[b,s,d] + pe[s,d]
//   x: float32 [B=8, S=4096, D=1024]
//   pe[s,d] = sin(val) if d even else cos(val),  val = s * 10000^(-2d/D)
//
// Memory-bound elementwise: 268 MB total traffic -> ~43 us roofline.
// One thread computes one float4 of pe (amortized over the 8 batch slices).

#define PE_D 1024
#define PE_S 4096
#define PE_B 8

__global__ __launch_bounds__(256) void
PositionalEncoderModule_48455821033878_kernel(const float* __restrict__ x,
                                              float* __restrict__ out) {
    const int tid = blockIdx.x * blockDim.x + threadIdx.x;   // over S*D/4
    const int d4  = tid & (PE_D / 4 - 1);                    // float4 index in row
    const int s   = tid >> 8;                                // tid / (D/4)
    const int d0  = d4 << 2;                                 // always even

    const float pos = (float)s;
    // 10000^(-2d/1024) = exp2( -2*log2(10000)/1024 * d )
    const float c = -0.0259525632413075175f;                 // -2*log2(1e4)/1024

    float4 pe;
    pe.x = sinf(pos * exp2f(c * (float)(d0 + 0)));           // even -> sin
    pe.y = cosf(pos * exp2f(c * (float)(d0 + 1)));           // odd  -> cos
    pe.z = sinf(pos * exp2f(c * (float)(d0 + 2)));
    pe.w = cosf(pos * exp2f(c * (float)(d0 + 3)));

    const size_t plane = (size_t)PE_S * PE_D;                // elements per batch
    const size_t base  = (size_t)s * PE_D + (size_t)d0;

#pragma unroll
    for (int b = 0; b < PE_B; ++b) {
        const float4 v = *(const float4*)(x + base + (size_t)b * plane);
        float4 r;
        r.x = v.x + pe.x;
        r.y = v.y + pe.y;
        r.z = v.z + pe.z;
        r.w = v.w + pe.w;
        *(float4*)(out + base + (size_t)b * plane) = r;
    }
}

extern "C" void kernel_launch(void* const* d_in, const int* in_sizes, int n_in,
                              void* d_out, int out_size, void* d_ws, size_t ws_size,
                              hipStream_t stream) {
    const float* x  = (const float*)d_in[0];
    float* out      = (float*)d_out;

    // S*D/4 threads, 256 per block
    const int n_threads = PE_S * PE_D / 4;                   // 1,048,576
    const int block = 256;
    const int grid  = n_threads / block;                     // 4096

    PositionalEncoderModule_48455821033878_kernel<<<grid, block, 0, stream>>>(x, out);
}

// Round 3
// 220.483 us; speedup vs baseline: 1.0878x; 1.0878x over previous
//
#include <hip/hip_runtime.h>
#include <hip/hip_bf16.h>
#include <math.h>

// out[b,s,d] = x[b,s,d] + pe[s,d];  x: fp32 [8, 4096, 1024]
// pe[s,d] = sin(s * 10000^(-2d/1024)) if d even else cos(...)
//
// R1: batch-amortized pe, latency-bound (2 TB/s, VALUBusy 5%) — serialized
//     8 ld/st per thread with only 32 VGPRs.
// R2: max-TLP structure but hand-written chain constants were wrong at 1e-5
//     rel — ×4000 rad phase amplification → absmax 0.133 (fail).
// R3: R2 structure + R1's per-element exp2f math (passed at 0.031 absmax).

#define PE_D 1024
#define PE_S 4096
#define PE_B 8

__global__ __launch_bounds__(256) void
PositionalEncoderModule_48455821033878_kernel(const float* __restrict__ x,
                                              float* __restrict__ out) {
    const int tid = blockIdx.x * blockDim.x + threadIdx.x;   // over B*S*D/4 = 8M
    const int d4  = tid & (PE_D / 4 - 1);                    // float4 index in row
    const int s   = (tid >> 8) & (PE_S - 1);                 // seq position
    const int d0  = d4 << 2;                                 // even

    // Issue the load first; pe math hides its latency.
    const size_t base = (size_t)tid * 4;
    const float4 v = *(const float4*)(x + base);

    const float pos = (float)s;
    // 10000^(-2d/1024) = exp2(c*d), c = -2*log2(1e4)/1024
    const float c = -0.025952563241307517f;

    float4 pe;
    pe.x = sinf(pos * exp2f(c * (float)(d0 + 0)));           // even -> sin
    pe.y = cosf(pos * exp2f(c * (float)(d0 + 1)));           // odd  -> cos
    pe.z = sinf(pos * exp2f(c * (float)(d0 + 2)));
    pe.w = cosf(pos * exp2f(c * (float)(d0 + 3)));

    float4 r;
    r.x = v.x + pe.x;
    r.y = v.y + pe.y;
    r.z = v.z + pe.z;
    r.w = v.w + pe.w;
    *(float4*)(out + base) = r;
}

extern "C" void kernel_launch(void* const* d_in, const int* in_sizes, int n_in,
                              void* d_out, int out_size, void* d_ws, size_t ws_size,
                              hipStream_t stream) {
    const float* x = (const float*)d_in[0];
    float* out     = (float*)d_out;

    const int n_threads = PE_B * PE_S * PE_D / 4;            // 8,388,608
    const int block = 256;
    const int grid  = n_threads / block;                     // 32768

    PositionalEncoderModule_48455821033878_kernel<<<grid, block, 0, stream>>>(x, out);
}